// Round 11
// baseline (23.447 us; speedup 1.0000x reference)
//
#include <hip/hip_runtime.h>
#include <math.h>

#define L 512
#define TILE_T 8          // per block; each of 4 waves owns 2 t's
#define NTHREADS 256
#define ZWIN 9.0f         // dropped pdf mass <= exp(-40.5): < 1e-10 effect on output
#define NXCD 8

static constexpr float EPS = 1e-6f;
static constexpr float INV_SQRT_2PI = 0.39894228040143267794f;

__global__ __launch_bounds__(NTHREADS, 8) void ge_kernel(
    const float* __restrict__ text,  // [B, L, D]
    const int*   __restrict__ durs,  // [B, L]
    float*       __restrict__ out,   // [B, T, D]
    int B, int D, int T, int tilesPerB, int nwg)
{
    __shared__ float2 s_mi[L];        // (mean, 1/sigma); every wave writes all (identical values)
    __shared__ float2 s_p[4][64];     // per-wave probs chunk: item -> (p_t0, p_t1)

    const int tid  = threadIdx.x;
    const int lane = tid & 63;
    const int wid  = tid >> 6;

    // XCD-aware bijective swizzle (nwg % NXCD == 0)
    const int orig = blockIdx.x;
    const int wg   = (nwg % NXCD == 0) ? (orig & (NXCD - 1)) * (nwg / NXCD) + (orig >> 3)
                                       : orig;
    const int b    = wg / tilesPerB;
    const int t0   = (wg % tilesPerB) * TILE_T;
    const int t0w  = t0 + (wid << 1);           // this wave's 2 t's

    // ---- wave-private full cumsum: lane owns rows 8*lane..8*lane+7 (no barriers) ----
    const int r0 = lane << 3;
    const int4* dp = (const int4*)(durs + (size_t)b * L + r0);
    const int4 da = dp[0];
    const int4 db = dp[1];
    int dv[8] = {da.x, da.y, da.z, da.w, db.x, db.y, db.z, db.w};
    int csum[8];
    {
        int run = 0;
        #pragma unroll
        for (int j = 0; j < 8; ++j) { run += dv[j]; csum[j] = run; }
        int v = run;
        #pragma unroll
        for (int off = 1; off < 64; off <<= 1) {
            int n = __shfl_up(v, off, 64);
            if (lane >= off) v += n;
        }
        const int excl = v - run;
        #pragma unroll
        for (int j = 0; j < 8; ++j) csum[j] += excl;   // inclusive cumsum
    }

    // ---- params to LDS + this wave's band [myMin, myMax] for its 2 t's ----
    const float tlo = (float)t0w + 0.5f;
    const float thi = (float)t0w + 1.5f;
    int myMin = L, myMax = -1;
    #pragma unroll
    for (int j = 0; j < 8; ++j) {
        const float d  = (float)dv[j];
        const float m  = (float)csum[j] + 0.5f * d;    // cumsum_incl + d/2
        const float sg = 0.5f * d + EPS;
        s_mi[r0 + j] = make_float2(m, 1.0f / sg);
        const float r = ZWIN * sg;
        if ((dv[j] >= 1) && (m + r >= tlo) && (m - r <= thi)) {
            myMin = min(myMin, r0 + j);
            myMax = max(myMax, r0 + j);
        }
    }
    #pragma unroll
    for (int off = 32; off > 0; off >>= 1) {
        myMin = min(myMin, __shfl_xor(myMin, off, 64));
        myMax = max(myMax, __shfl_xor(myMax, off, 64));
    }
    // this wave wrote every s_mi entry itself -> wave-local fence suffices
    asm volatile("s_waitcnt lgkmcnt(0)" ::: "memory");
    __builtin_amdgcn_sched_barrier(0);

    // ---- chunked band sweep: per-lane probs -> per-wave LDS -> broadcast FMA ----
    const float tqa = (float)t0w + 0.5f;
    float4 a0 = {0,0,0,0}, a1 = {0,0,0,0};
    float  ps0 = 0.f, ps1 = 0.f;
    const float* tb = text + (size_t)b * L * D + (lane << 2);

    for (int cbase = myMin; cbase <= myMax; cbase += 64) {
        const int nb = min(64, myMax - cbase + 1);

        float2 pv = {0.f, 0.f};
        if (lane < nb) {
            const float2 mi = s_mi[cbase + lane];
            const float F  = -0.5f * mi.y * mi.y;
            const float c  = mi.y * INV_SQRT_2PI;
            const float u0 = tqa - mi.x;
            const float u1 = u0 + 1.f;
            pv.x = __expf(F * u0 * u0) * c;
            pv.y = __expf(F * u1 * u1) * c;
        }
        if (cbase != myMin) {   // WAR fence before overwriting prior chunk
            asm volatile("s_waitcnt lgkmcnt(0)" ::: "memory");
            __builtin_amdgcn_sched_barrier(0);
        }
        s_p[wid][lane] = pv;
        asm volatile("s_waitcnt lgkmcnt(0)" ::: "memory");   // wave-local RAW fence
        __builtin_amdgcn_sched_barrier(0);

        // FMA loop, 2-deep text prefetch; s_p zero-padded past nb
        const int niter = (nb + 1) & ~1;   // even
        float4 v0 = *(const float4*)(tb + (size_t)min(cbase + 0, L - 1) * D);
        float4 v1 = *(const float4*)(tb + (size_t)min(cbase + 1, L - 1) * D);
        for (int i = 0; i < niter; i += 2) {
            const float4 w0 = v0, w1 = v1;
            v0 = *(const float4*)(tb + (size_t)min(cbase + i + 2, L - 1) * D);
            v1 = *(const float4*)(tb + (size_t)min(cbase + i + 3, L - 1) * D);
            const float2 q0 = s_p[wid][i];         // wave-uniform broadcast (8B)
            const float2 q1 = s_p[wid][i + 1];
            ps0 += q0.x + q1.x;
            ps1 += q0.y + q1.y;
            a0.x += q0.x*w0.x + q1.x*w1.x; a0.y += q0.x*w0.y + q1.x*w1.y;
            a0.z += q0.x*w0.z + q1.x*w1.z; a0.w += q0.x*w0.w + q1.x*w1.w;
            a1.x += q0.y*w0.x + q1.y*w1.x; a1.y += q0.y*w0.y + q1.y*w1.y;
            a1.z += q0.y*w0.z + q1.y*w1.z; a1.w += q0.y*w0.w + q1.y*w1.w;
        }
    }

    // ---- normalize + store (wave writes its 2 t rows) ----
    const float rn0 = 1.0f / (ps0 + EPS);
    const float rn1 = 1.0f / (ps1 + EPS);
    float* ob = out + ((size_t)b * T + t0w) * D + (lane << 2);
    if (t0w + 0 < T) *(float4*)(ob + 0*(size_t)D) = make_float4(a0.x*rn0, a0.y*rn0, a0.z*rn0, a0.w*rn0);
    if (t0w + 1 < T) *(float4*)(ob + 1*(size_t)D) = make_float4(a1.x*rn1, a1.y*rn1, a1.z*rn1, a1.w*rn1);
}

extern "C" void kernel_launch(void* const* d_in, const int* in_sizes, int n_in,
                              void* d_out, int out_size, void* d_ws, size_t ws_size,
                              hipStream_t stream) {
    const float* text = (const float*)d_in[0];
    const int*   durs = (const int*)d_in[1];
    float*       out  = (float*)d_out;

    const int BL = in_sizes[1];        // B * L
    const int D  = in_sizes[0] / BL;   // 256
    const int B  = BL / L;             // 16
    const int T  = out_size / (B * D); // 2048
    const int tilesPerB = (T + TILE_T - 1) / TILE_T;   // 256
    const int nwg = B * tilesPerB;     // 4096 -> 2 generations at 8 blocks/CU

    ge_kernel<<<dim3(nwg), dim3(NTHREADS), 0, stream>>>(
        text, durs, out, B, D, T, tilesPerB, nwg);
}